// Round 2
// baseline (404.506 us; speedup 1.0000x reference)
//
#include <hip/hip_runtime.h>

#define N_NODES 20000
#define N_EDGES 200000
#define HID 128

typedef unsigned short u16;
using bf16x8 = __attribute__((ext_vector_type(8))) __bf16;
using f32x4  = __attribute__((ext_vector_type(4))) float;

#define LGKM_WAIT asm volatile("s_waitcnt lgkmcnt(0)" ::: "memory")

__device__ __forceinline__ u16 f2bf(float f) {
  union { float f; unsigned u; } v; v.f = f;
  unsigned u = v.u;
  return (u16)((u + 0x7FFFu + ((u >> 16) & 1u)) >> 16);
}
__device__ __forceinline__ float bf2f(unsigned s) {
  union { unsigned u; float f; } v; v.u = s << 16;
  return v.f;
}
__device__ __forceinline__ bf16x8 ld8(const u16* p) { return *(const bf16x8*)p; }

__device__ __forceinline__ void zero8(f32x4 acc[8][2]) {
#pragma unroll
  for (int i = 0; i < 8; ++i) {
    acc[i][0] = (f32x4){0.f, 0.f, 0.f, 0.f};
    acc[i][1] = (f32x4){0.f, 0.f, 0.f, 0.f};
  }
}

// D^T = W x X^T per wave: A = packed W (global, coalesced), B = per-edge fragments
// (lambda). Wave owns 32 edges (2 n-tiles) x 128 out-ch (8 m-tiles).
template <int KSTEPS, typename F>
__device__ __forceinline__ void wgemm(const u16* __restrict__ PW, F bfrag,
                                      f32x4 acc[8][2], int lane) {
  const u16* pa = PW + lane * 8;
#pragma unroll
  for (int ks = 0; ks < KSTEPS; ++ks) {
    bf16x8 b0 = bfrag(ks, 0);
    bf16x8 b1 = bfrag(ks, 1);
#pragma unroll
    for (int mt = 0; mt < 8; ++mt) {
      bf16x8 a = ld8(pa + ks * 4096 + mt * 512);
      acc[mt][0] = __builtin_amdgcn_mfma_f32_16x16x32_bf16(a, b0, acc[mt][0], 0, 0, 0);
      acc[mt][1] = __builtin_amdgcn_mfma_f32_16x16x32_bf16(a, b1, acc[mt][1], 0, 0, 0);
    }
  }
}

// C/D: col = lane&15 = edge-in-tile, row = (lane>>4)*4 + reg = out-ch. Store slab
// as [edge][ch], stride 136 u16: b64 stores (4 consecutive ch), conflict-free.
template <bool RELU>
__device__ __forceinline__ void epi_store(u16* slab, const f32x4 acc[8][2],
                                          const float* __restrict__ bias, int lane) {
  const int ln = lane & 15, q = lane >> 4;
#pragma unroll
  for (int mt = 0; mt < 8; ++mt) {
    float4 bv = *(const float4*)(bias + mt * 16 + q * 4);
#pragma unroll
    for (int nt = 0; nt < 2; ++nt) {
      union { u16 s[4]; uint2 u; } t;
#pragma unroll
      for (int r = 0; r < 4; ++r) {
        float v = acc[mt][nt][r] + ((const float*)&bv)[r];
        if (RELU) v = fmaxf(v, 0.f);
        t.s[r] = f2bf(v);
      }
      *(uint2*)(slab + (nt * 16 + ln) * 136 + mt * 16 + q * 4) = t.u;
    }
  }
}

__device__ __forceinline__ void flush_slab(const u16* slab, u16* __restrict__ gout,
                                           int e0w, int lane) {
  const int ebase = lane >> 4, piece = lane & 15;
#pragma unroll
  for (int it = 0; it < 8; ++it) {
    int e = it * 4 + ebase;
    uint4 v = *(const uint4*)(slab + e * 136 + piece * 8);
    *(uint4*)(gout + (size_t)(e0w + e) * HID + piece * 8) = v;
  }
}

// ---- fold encoder (conv1d+mean) and fuse into M[128x20], C0[128], Wnt[128] ----
__global__ void k_fold(const float* __restrict__ emb, const float* __restrict__ conv_w,
                       const float* __restrict__ conv_b, const float* __restrict__ fuse_w,
                       const float* __restrict__ fuse_b, float* __restrict__ Mt,
                       float* __restrict__ C0, float* __restrict__ Wnt) {
  __shared__ float Ash[128][21];
  int o = threadIdx.x;  // 128 threads
  {
    float b0 = conv_b[o];
#pragma unroll
    for (int p = 0; p < 5; ++p) {
#pragma unroll
      for (int i = 0; i < 8; ++i) {
        float s = 0.f;
#pragma unroll
        for (int k = 0; k < 3; ++k) {
          int t = p + 1 - k;
          if (t >= 0 && t < 5) s += conv_w[(o * 8 + i) * 3 + k];
        }
        s *= 0.2f;
        if (i < 4) Ash[o][p * 4 + i] = s;
        else b0 += emb[p * 4 + (i - 4)] * s;
      }
    }
    Ash[o][20] = b0;
  }
  __syncthreads();
  float m[20];
#pragma unroll
  for (int qq = 0; qq < 20; ++qq) m[qq] = 0.f;
  float c0 = fuse_b[o];
  for (int j = 0; j < 128; ++j) {
    float w = fuse_w[o * 129 + j];
#pragma unroll
    for (int qq = 0; qq < 20; ++qq) m[qq] += w * Ash[j][qq];
    c0 += w * Ash[j][20];
  }
#pragma unroll
  for (int qq = 0; qq < 20; ++qq) Mt[qq * 128 + o] = m[qq];
  C0[o] = c0;
  Wnt[o] = fuse_w[o * 129 + 128];
}

// ---- pack weight matrices [128][Kin] into bf16 fragment order (A or B role) ----
struct PackArgs {
  const float* src[7];
  u16* dst[7];
  int Kin[7];
  int ksCum[8];
};

__global__ void k_pack(PackArgs pa) {
  int bk = blockIdx.x;
  int mi = 0;
  while (bk >= pa.ksCum[mi + 1]) ++mi;
  int ks = bk - pa.ksCum[mi];
  const float* W = pa.src[mi];
  u16* D = pa.dst[mi] + ks * 4096;
  int Kin = pa.Kin[mi];
#pragma unroll
  for (int t = 0; t < 16; ++t) {
    int el = t * 256 + (int)threadIdx.x;
    int j = el & 7, ln = (el >> 3) & 63, ntile = el >> 9;
    int k = ks * 32 + ((ln >> 4) << 3) + j;
    int n = ntile * 16 + (ln & 15);
    float v = (k < Kin) ? W[n * Kin + k] : 0.0f;
    D[el] = f2bf(v);
  }
}

// ---- node encoder: h2[n] = M @ xflat[n] + C0 + Wnt*nt  (bf16 out) ----
__global__ __launch_bounds__(256) void k_encode(const float* __restrict__ x,
                                                const float* __restrict__ node_type,
                                                const float* __restrict__ Mt,
                                                const float* __restrict__ C0,
                                                const float* __restrict__ Wnt,
                                                u16* __restrict__ h2) {
  __shared__ float xs[2][20];
  int local = threadIdx.x >> 7, o = threadIdx.x & 127;
  int node = blockIdx.x * 2 + local;
  if (threadIdx.x < 40) {
    int nn = threadIdx.x / 20, qq = threadIdx.x % 20;
    xs[nn][qq] = x[(blockIdx.x * 2 + nn) * 20 + qq];
  }
  __syncthreads();
  float acc = C0[o] + Wnt[o] * node_type[node];
#pragma unroll
  for (int qq = 0; qq < 20; ++qq) acc += xs[local][qq] * Mt[qq * 128 + o];
  h2[node * HID + o] = f2bf(acc);
}

// ---- gnn1: barrier-free per-wave. ea1 = g1e(h2[row],h2[col],eattr); h3 = g1n(h2[row],ea1)
__global__ __launch_bounds__(256, 3) void k_gnn1(
    const int* __restrict__ eidx, const float* __restrict__ eattr,
    const u16* __restrict__ h2, const u16* __restrict__ pW1, const u16* __restrict__ pW2,
    const u16* __restrict__ pW3, const u16* __restrict__ pW4, const float* __restrict__ b1,
    const float* __restrict__ b2, const float* __restrict__ b3, const float* __restrict__ b4,
    u16* __restrict__ ea1, u16* __restrict__ h3) {
  __shared__ __align__(16) u16 lds[4][32 * 136];
  const int tid = threadIdx.x, lane = tid & 63, wave = tid >> 6;
  const int e0w = blockIdx.x * 128 + wave * 32;
  if (e0w >= N_EDGES) return;
  u16* slab = lds[wave];
  const int ln = lane & 15, q = lane >> 4;
  const int ea_i = e0w + ln, eb_i = e0w + 16 + ln;
  const int* rowI = eidx;
  const int* colI = eidx + N_EDGES;
  const int ir0 = rowI[ea_i], ir1 = rowI[eb_i], ic0 = colI[ea_i], ic1 = colI[eb_i];
  const u16* hr[2] = {h2 + (size_t)ir0 * HID + q * 8, h2 + (size_t)ir1 * HID + q * 8};
  const u16* hc[2] = {h2 + (size_t)ic0 * HID + q * 8, h2 + (size_t)ic1 * HID + q * 8};

  f32x4 acc[8][2];
  auto sfrag = [&](int ks, int nt) -> bf16x8 {
    return ld8(slab + (nt * 16 + ln) * 136 + ks * 32 + q * 8);
  };

  // GEMM1: K=288 (260 live): [h2row | h2col | eattr(4)+pad]
  zero8(acc);
  {
    auto bfrag = [&](int ks, int nt) -> bf16x8 {
      if (ks < 4) return ld8(hr[nt] + ks * 32);
      if (ks < 8) return ld8(hc[nt] + (ks - 4) * 32);
      union { u16 s[8]; uint4 u; bf16x8 v; } t;
      t.u = make_uint4(0u, 0u, 0u, 0u);
      if (q == 0) {
        const float* ap = eattr + (size_t)(nt ? eb_i : ea_i) * 4;
        t.s[0] = f2bf(ap[0]); t.s[1] = f2bf(ap[1]);
        t.s[2] = f2bf(ap[2]); t.s[3] = f2bf(ap[3]);
      }
      return t.v;
    };
    wgemm<9>(pW1, bfrag, acc, lane);
  }
  epi_store<true>(slab, acc, b1, lane);  // h (relu) -> slab
  LGKM_WAIT;

  zero8(acc);
  wgemm<4>(pW2, sfrag, acc, lane);       // ea1 = W2 x h^T
  epi_store<false>(slab, acc, b2, lane); // ea1 -> slab (after all h reads; in-order DS)
  LGKM_WAIT;
  flush_slab(slab, ea1, e0w, lane);

  if (e0w < N_NODES) {  // h3 only ever gathered at indices < N
    zero8(acc);
    {
      auto bfrag = [&](int ks, int nt) -> bf16x8 {
        if (ks < 4) return ld8(hr[nt] + ks * 32);
        return ld8(slab + (nt * 16 + ln) * 136 + (ks - 4) * 32 + q * 8);
      };
      wgemm<8>(pW3, bfrag, acc, lane);   // K=256: [h2row | ea1]
    }
    epi_store<true>(slab, acc, b3, lane);
    LGKM_WAIT;
    zero8(acc);
    wgemm<4>(pW4, sfrag, acc, lane);
    epi_store<false>(slab, acc, b4, lane);
    LGKM_WAIT;
    flush_slab(slab, h3, e0w, lane);
  }
}

// ---- gnn2 + fm1 + BN-stats, barrier-free per-wave ----
__global__ __launch_bounds__(256, 3) void k_gnn2(
    const int* __restrict__ eidx, const u16* __restrict__ h3, u16* ea1z,
    const u16* __restrict__ pW5, const u16* __restrict__ pW6, const u16* __restrict__ pW7,
    const float* __restrict__ b5, const float* __restrict__ b6, const float* __restrict__ b7,
    float* __restrict__ partials) {
  __shared__ __align__(16) u16 lds[4][32 * 136];
  const int tid = threadIdx.x, lane = tid & 63, wave = tid >> 6;
  const int e0w = blockIdx.x * 128 + wave * 32;
  const int pbase = ((int)blockIdx.x * 4 + wave) * 256;
  if (e0w >= N_EDGES) {  // zero-fill partials so k_reduce never reads poison
#pragma unroll
    for (int j = 0; j < 4; ++j) partials[pbase + lane * 4 + j] = 0.f;
    return;
  }
  u16* slab = lds[wave];
  const int ln = lane & 15, q = lane >> 4;
  const int ea_i = e0w + ln, eb_i = e0w + 16 + ln;
  const int* rowI = eidx;
  const int* colI = eidx + N_EDGES;
  const int ir0 = rowI[ea_i], ir1 = rowI[eb_i], ic0 = colI[ea_i], ic1 = colI[eb_i];
  const u16* hr[2] = {h3 + (size_t)ir0 * HID + q * 8, h3 + (size_t)ir1 * HID + q * 8};
  const u16* hc[2] = {h3 + (size_t)ic0 * HID + q * 8, h3 + (size_t)ic1 * HID + q * 8};
  const u16* he[2] = {ea1z + (size_t)ea_i * HID + q * 8, ea1z + (size_t)eb_i * HID + q * 8};

  f32x4 acc[8][2];
  auto sfrag = [&](int ks, int nt) -> bf16x8 {
    return ld8(slab + (nt * 16 + ln) * 136 + ks * 32 + q * 8);
  };

  // GEMM1: K=384: [h3row | h3col | ea1]
  zero8(acc);
  {
    auto bfrag = [&](int ks, int nt) -> bf16x8 {
      if (ks < 4) return ld8(hr[nt] + ks * 32);
      if (ks < 8) return ld8(hc[nt] + (ks - 4) * 32);
      return ld8(he[nt] + (ks - 8) * 32);
    };
    wgemm<12>(pW5, bfrag, acc, lane);
  }
  epi_store<true>(slab, acc, b5, lane);
  LGKM_WAIT;

  zero8(acc);
  wgemm<4>(pW6, sfrag, acc, lane);       // ea2
  epi_store<false>(slab, acc, b6, lane);
  LGKM_WAIT;

  zero8(acc);
  wgemm<4>(pW7, sfrag, acc, lane);       // z = fm1(ea2)
  epi_store<false>(slab, acc, b7, lane);
  LGKM_WAIT;

  // flush z (overwrites ea1 rows of this wave's own edges — already consumed) + BN stats
  float s[8], sq[8];
#pragma unroll
  for (int j = 0; j < 8; ++j) { s[j] = 0.f; sq[j] = 0.f; }
  {
    const int ebase = q, piece = ln;
#pragma unroll
    for (int it = 0; it < 8; ++it) {
      int e = it * 4 + ebase;
      uint4 v = *(const uint4*)(slab + e * 136 + piece * 8);
      *(uint4*)(ea1z + (size_t)(e0w + e) * HID + piece * 8) = v;
      unsigned w4[4] = {v.x, v.y, v.z, v.w};
#pragma unroll
      for (int k = 0; k < 4; ++k) {
        float lo = bf2f(w4[k] & 0xffffu), hi = bf2f(w4[k] >> 16);
        s[2 * k] += lo;  sq[2 * k] += lo * lo;
        s[2 * k + 1] += hi; sq[2 * k + 1] += hi * hi;
      }
    }
  }
#pragma unroll
  for (int j = 0; j < 8; ++j) {
    s[j] += __shfl_xor(s[j], 16);  s[j] += __shfl_xor(s[j], 32);
    sq[j] += __shfl_xor(sq[j], 16); sq[j] += __shfl_xor(sq[j], 32);
  }
  if (lane < 16) {
    float4 a0 = {s[0], s[1], s[2], s[3]}, a1 = {s[4], s[5], s[6], s[7]};
    float4 c0 = {sq[0], sq[1], sq[2], sq[3]}, c1 = {sq[4], sq[5], sq[6], sq[7]};
    *(float4*)&partials[pbase + lane * 8]       = a0;
    *(float4*)&partials[pbase + lane * 8 + 4]   = a1;
    *(float4*)&partials[pbase + 128 + lane * 8] = c0;
    *(float4*)&partials[pbase + 128 + lane * 8 + 4] = c1;
  }
}

#define NPROWS (1563 * 4)

__global__ void k_reduce(const float* __restrict__ partials, float* __restrict__ bnacc) {
  int t = threadIdx.x;  // 256
  float s = 0.f;
  for (int b = blockIdx.x; b < NPROWS; b += 64) s += partials[b * 256 + t];
  atomicAdd(&bnacc[t], s);
}

__global__ void k_bnfin(const float* __restrict__ bnacc, const float* __restrict__ bn_g,
                        const float* __restrict__ bn_b, float* __restrict__ ss) {
  int t = threadIdx.x;  // 128
  float inv = 1.0f / (float)N_EDGES;
  float mu = bnacc[t] * inv;
  float var = bnacc[128 + t] * inv - mu * mu;
  float sc = bn_g[t] * rsqrtf(var + 1e-5f);
  ss[t] = sc;
  ss[128 + t] = bn_b[t] - mu * sc;
}

// ---- head: out = fm_w2 @ relu(BN(z)) + fm_b2 ----
__global__ __launch_bounds__(256) void k_head(const u16* __restrict__ z,
                                              const float* __restrict__ ss,
                                              const float* __restrict__ w2,
                                              const float* __restrict__ b2,
                                              float* __restrict__ out) {
  const int lane = threadIdx.x & 63;
  const int wv = (int)(blockIdx.x * blockDim.x + threadIdx.x) >> 6;
  const int nwv = (int)(gridDim.x * blockDim.x) >> 6;
  const int c0 = lane * 2, c1 = c0 + 1;
  float s0 = ss[c0], s1 = ss[c1], h0 = ss[128 + c0], h1 = ss[128 + c1];
  float w00 = w2[c0], w01 = w2[c1], w10 = w2[128 + c0], w11 = w2[128 + c1];
  float w20 = w2[256 + c0], w21 = w2[256 + c1];
  float bb0 = b2[0], bb1 = b2[1], bb2 = b2[2];
  for (int e = wv; e < N_EDGES; e += nwv) {
    unsigned zz = *(const unsigned*)(z + e * HID + c0);
    float r0 = fmaxf(bf2f(zz & 0xffffu) * s0 + h0, 0.f);
    float r1 = fmaxf(bf2f(zz >> 16) * s1 + h1, 0.f);
    float p0 = r0 * w00 + r1 * w01;
    float p1 = r0 * w10 + r1 * w11;
    float p2 = r0 * w20 + r1 * w21;
#pragma unroll
    for (int off = 32; off > 0; off >>= 1) {
      p0 += __shfl_xor(p0, off);
      p1 += __shfl_xor(p1, off);
      p2 += __shfl_xor(p2, off);
    }
    if (lane == 0) {
      out[e * 3 + 0] = p0 + bb0;
      out[e * 3 + 1] = p1 + bb1;
      out[e * 3 + 2] = p2 + bb2;
    }
  }
}

extern "C" void kernel_launch(void* const* d_in, const int* in_sizes, int n_in,
                              void* d_out, int out_size, void* d_ws, size_t ws_size,
                              hipStream_t stream) {
  const float* x         = (const float*)d_in[0];
  const int* eidx        = (const int*)d_in[1];
  const float* eattr     = (const float*)d_in[2];
  const float* node_type = (const float*)d_in[4];
  const float* emb       = (const float*)d_in[5];
  const float* conv_w    = (const float*)d_in[6];
  const float* conv_b    = (const float*)d_in[7];
  const float* fuse_w    = (const float*)d_in[8];
  const float* fuse_b    = (const float*)d_in[9];
  const float* g1e_w1    = (const float*)d_in[10];
  const float* g1e_b1    = (const float*)d_in[11];
  const float* g1e_w2    = (const float*)d_in[12];
  const float* g1e_b2    = (const float*)d_in[13];
  const float* g1n_w1    = (const float*)d_in[14];
  const float* g1n_b1    = (const float*)d_in[15];
  const float* g1n_w2    = (const float*)d_in[16];
  const float* g1n_b2    = (const float*)d_in[17];
  const float* g2e_w1    = (const float*)d_in[18];
  const float* g2e_b1    = (const float*)d_in[19];
  const float* g2e_w2    = (const float*)d_in[20];
  const float* g2e_b2    = (const float*)d_in[21];
  // d_in[22..25] = g2n_* : dead code in the reference (output unused)
  const float* fm_w1     = (const float*)d_in[26];
  const float* fm_b1     = (const float*)d_in[27];
  const float* bn_g      = (const float*)d_in[28];
  const float* bn_b      = (const float*)d_in[29];
  const float* fm_w2     = (const float*)d_in[30];
  const float* fm_b2     = (const float*)d_in[31];
  float* out = (float*)d_out;

  char* ws = (char*)d_ws;
  size_t off = 0;
  auto take = [&](size_t bytes) {
    void* p = ws + off;
    off = (off + bytes + 255) & ~(size_t)255;
    return p;
  };
  u16* h2   = (u16*)take((size_t)N_NODES * HID * 2);
  u16* h3   = (u16*)take((size_t)20032 * HID * 2);  // only rows < N ever gathered
  u16* ea1z = (u16*)take((size_t)N_EDGES * HID * 2);
  float* Mt    = (float*)take(20 * 128 * 4);
  float* C0    = (float*)take(128 * 4);
  float* Wnt   = (float*)take(128 * 4);
  float* bnacc = (float*)take(256 * 4);
  float* bnss  = (float*)take(256 * 4);
  float* partials = (float*)take((size_t)NPROWS * 256 * 4);
  u16* pW1 = (u16*)take(9 * 4096 * 2);
  u16* pW2 = (u16*)take(4 * 4096 * 2);
  u16* pW3 = (u16*)take(8 * 4096 * 2);
  u16* pW4 = (u16*)take(4 * 4096 * 2);
  u16* pW5 = (u16*)take(12 * 4096 * 2);
  u16* pW6 = (u16*)take(4 * 4096 * 2);
  u16* pW7 = (u16*)take(4 * 4096 * 2);

  hipMemsetAsync(bnacc, 0, 256 * 4, stream);
  k_fold<<<1, 128, 0, stream>>>(emb, conv_w, conv_b, fuse_w, fuse_b, Mt, C0, Wnt);

  PackArgs pa;
  const float* srcs[7] = {g1e_w1, g1e_w2, g1n_w1, g1n_w2, g2e_w1, g2e_w2, fm_w1};
  u16* dsts[7] = {pW1, pW2, pW3, pW4, pW5, pW6, pW7};
  int kins[7] = {260, 128, 256, 128, 384, 128, 128};
  int kst[7] = {9, 4, 8, 4, 12, 4, 4};
  int cum = 0;
  for (int i = 0; i < 7; ++i) {
    pa.src[i] = srcs[i]; pa.dst[i] = dsts[i]; pa.Kin[i] = kins[i];
    pa.ksCum[i] = cum; cum += kst[i];
  }
  pa.ksCum[7] = cum;  // 45
  k_pack<<<45, 256, 0, stream>>>(pa);

  k_encode<<<N_NODES / 2, 256, 0, stream>>>(x, node_type, Mt, C0, Wnt, h2);
  const int NB = (N_EDGES + 127) / 128;  // 1563
  k_gnn1<<<NB, 256, 0, stream>>>(eidx, eattr, h2, pW1, pW2, pW3, pW4,
                                 g1e_b1, g1e_b2, g1n_b1, g1n_b2, ea1z, h3);
  k_gnn2<<<NB, 256, 0, stream>>>(eidx, h3, ea1z, pW5, pW6, pW7,
                                 g2e_b1, g2e_b2, fm_b1, partials);
  k_reduce<<<64, 256, 0, stream>>>(partials, bnacc);
  k_bnfin<<<1, 128, 0, stream>>>(bnacc, bn_g, bn_b, bnss);
  k_head<<<512, 256, 0, stream>>>(ea1z, bnss, fm_w2, fm_b2, out);
}

// Round 5
// 288.301 us; speedup vs baseline: 1.4031x; 1.4031x over previous
//
#include <hip/hip_runtime.h>

#define N_NODES 20000
#define N_EDGES 200000
#define HID 128
#define STR 136  // LDS row stride in u16: 272B rows -> every b128 access 16B-aligned
#define NBLK 3125

typedef unsigned short u16;
using bf16x8 = __attribute__((ext_vector_type(8))) __bf16;
using f32x4  = __attribute__((ext_vector_type(4))) float;

__device__ __forceinline__ u16 f2bf(float f) {
  union { float f; unsigned u; } v; v.f = f;
  unsigned u = v.u;
  return (u16)((u + 0x7FFFu + ((u >> 16) & 1u)) >> 16);
}
__device__ __forceinline__ float bf2f(unsigned s) {
  union { unsigned u; float f; } v; v.u = s << 16;
  return v.f;
}
__device__ __forceinline__ bf16x8 ld8(const u16* p) { return *(const bf16x8*)p; }

__device__ __forceinline__ void zero_acc(f32x4 acc[4][2]) {
#pragma unroll
  for (int i = 0; i < 4; ++i) {
    acc[i][0] = (f32x4){0.f, 0.f, 0.f, 0.f};
    acc[i][1] = (f32x4){0.f, 0.f, 0.f, 0.f};
  }
}

// GEMM: D[64 edges][128 ch] += A(edges, via afrag)[64][K] * B(packed W)[K][128].
// Wave w owns n-tiles {2w,2w+1}. Depth-2 explicit B prefetch ring hides L2 latency.
template <int KSTEPS, typename AF>
__device__ __forceinline__ void wgemm(const u16* __restrict__ PW, AF afrag,
                                      f32x4 acc[4][2], int lane, int wave) {
  const u16* pb = PW + (wave * 2 * 64 + lane) * 8;
  bf16x8 b0[2], b1[2];
  b0[0] = ld8(pb);
  b1[0] = ld8(pb + 512);
#pragma unroll
  for (int ks = 0; ks < KSTEPS; ++ks) {
    const int cur = ks & 1, nxt = cur ^ 1;
    if (ks + 1 < KSTEPS) {
      b0[nxt] = ld8(pb + (ks + 1) * 4096);
      b1[nxt] = ld8(pb + (ks + 1) * 4096 + 512);
    }
#pragma unroll
    for (int mt = 0; mt < 4; ++mt) {
      bf16x8 a = afrag(ks, mt);
      acc[mt][0] = __builtin_amdgcn_mfma_f32_16x16x32_bf16(a, b0[cur], acc[mt][0], 0, 0, 0);
      acc[mt][1] = __builtin_amdgcn_mfma_f32_16x16x32_bf16(a, b1[cur], acc[mt][1], 0, 0, 0);
    }
  }
}

// C/D: row(edge) = mt*16 + (lane>>4)*4 + r, col(ch) = wave*32 + nt*16 + (lane&15).
template <bool RELU>
__device__ __forceinline__ void epi_store(u16* buf, const f32x4 acc[4][2],
                                          const float* __restrict__ bias,
                                          int lane, int wave) {
  const int c = lane & 15, q = lane >> 4;
  const float bb0 = bias[wave * 32 + c], bb1 = bias[wave * 32 + 16 + c];
#pragma unroll
  for (int mt = 0; mt < 4; ++mt)
#pragma unroll
    for (int nt = 0; nt < 2; ++nt) {
      const float bb = nt ? bb1 : bb0;
      const int col = wave * 32 + nt * 16 + c;
#pragma unroll
      for (int r = 0; r < 4; ++r) {
        float v = acc[mt][nt][r] + bb;
        if (RELU) v = fmaxf(v, 0.f);
        buf[(mt * 16 + q * 4 + r) * STR + col] = f2bf(v);
      }
    }
}

__device__ __forceinline__ void flush_buf(const u16* buf, u16* __restrict__ gout,
                                          int e0, int tid) {
#pragma unroll
  for (int it = 0; it < 4; ++it) {
    int cid = tid + it * 256, e = cid >> 4, p = cid & 15;
    uint4 v = *(const uint4*)(buf + e * STR + p * 8);
    *(uint4*)(gout + (size_t)(e0 + e) * HID + p * 8) = v;
  }
}

// ---- fold encoder (conv1d+mean) and fuse into M[128x20], C0[128], Wnt[128] ----
__global__ void k_fold(const float* __restrict__ emb, const float* __restrict__ conv_w,
                       const float* __restrict__ conv_b, const float* __restrict__ fuse_w,
                       const float* __restrict__ fuse_b, float* __restrict__ Mt,
                       float* __restrict__ C0, float* __restrict__ Wnt) {
  __shared__ float Ash[128][21];
  int o = threadIdx.x;  // 128 threads
  {
    float b0 = conv_b[o];
#pragma unroll
    for (int p = 0; p < 5; ++p) {
#pragma unroll
      for (int i = 0; i < 8; ++i) {
        float s = 0.f;
#pragma unroll
        for (int k = 0; k < 3; ++k) {
          int t = p + 1 - k;
          if (t >= 0 && t < 5) s += conv_w[(o * 8 + i) * 3 + k];
        }
        s *= 0.2f;
        if (i < 4) Ash[o][p * 4 + i] = s;
        else b0 += emb[p * 4 + (i - 4)] * s;
      }
    }
    Ash[o][20] = b0;
  }
  __syncthreads();
  float m[20];
#pragma unroll
  for (int qq = 0; qq < 20; ++qq) m[qq] = 0.f;
  float c0 = fuse_b[o];
  for (int j = 0; j < 128; ++j) {
    float w = fuse_w[o * 129 + j];
#pragma unroll
    for (int qq = 0; qq < 20; ++qq) m[qq] += w * Ash[j][qq];
    c0 += w * Ash[j][20];
  }
#pragma unroll
  for (int qq = 0; qq < 20; ++qq) Mt[qq * 128 + o] = m[qq];
  C0[o] = c0;
  Wnt[o] = fuse_w[o * 129 + 128];
}

// ---- pack weight matrices [128][Kin] into bf16 B-fragment order ----
struct PackArgs {
  const float* src[7];
  u16* dst[7];
  int Kin[7];
  int ksCum[8];
};

__global__ void k_pack(PackArgs pa) {
  int bk = blockIdx.x;
  int mi = 0;
  while (bk >= pa.ksCum[mi + 1]) ++mi;
  int ks = bk - pa.ksCum[mi];
  const float* W = pa.src[mi];
  u16* D = pa.dst[mi] + ks * 4096;
  int Kin = pa.Kin[mi];
#pragma unroll
  for (int t = 0; t < 16; ++t) {
    int el = t * 256 + (int)threadIdx.x;
    int j = el & 7, ln = (el >> 3) & 63, ntile = el >> 9;
    int k = ks * 32 + ((ln >> 4) << 3) + j;
    int n = ntile * 16 + (ln & 15);
    float v = (k < Kin) ? W[n * Kin + k] : 0.0f;
    D[el] = f2bf(v);
  }
}

// ---- node encoder ----
__global__ __launch_bounds__(256) void k_encode(const float* __restrict__ x,
                                                const float* __restrict__ node_type,
                                                const float* __restrict__ Mt,
                                                const float* __restrict__ C0,
                                                const float* __restrict__ Wnt,
                                                u16* __restrict__ h2) {
  __shared__ float xs[2][20];
  int local = threadIdx.x >> 7, o = threadIdx.x & 127;
  int node = blockIdx.x * 2 + local;
  if (threadIdx.x < 40) {
    int nn = threadIdx.x / 20, qq = threadIdx.x % 20;
    xs[nn][qq] = x[(blockIdx.x * 2 + nn) * 20 + qq];
  }
  __syncthreads();
  float acc = C0[o] + Wnt[o] * node_type[node];
#pragma unroll
  for (int qq = 0; qq < 20; ++qq) acc += xs[local][qq] * Mt[qq * 128 + o];
  h2[node * HID + o] = f2bf(acc);
}

// ---- gnn1: ea1 = g1e(h2[row],h2[col],eattr); h3 = g1n(h2[row],ea1) for e0<N ----
__global__ __launch_bounds__(256, 3) void k_gnn1(
    const int* __restrict__ eidx, const float* __restrict__ eattr,
    const u16* __restrict__ h2, const u16* __restrict__ pW1, const u16* __restrict__ pW2,
    const u16* __restrict__ pW3, const u16* __restrict__ pW4, const float* __restrict__ b1,
    const float* __restrict__ b2, const float* __restrict__ b3, const float* __restrict__ b4,
    u16* __restrict__ ea1, u16* __restrict__ h3) {
  __shared__ __align__(16) u16 B0[64 * STR], B1[64 * STR], B2[64 * STR];
  const int tid = threadIdx.x, lane = tid & 63, wave = tid >> 6;
  const int e0 = blockIdx.x * 64;
  const int* rowI = eidx;
  const int* colI = eidx + N_EDGES;
  const int idr = rowI[e0 + lane], idc = colI[e0 + lane];
  const u16* hrow = h2 + (size_t)idr * HID;
  const u16* hcol = h2 + (size_t)idc * HID;

  // stage: lane owns edge `lane`. 32 pieces/edge total: waves 0,1 cover the 16
  // pieces of h2[row]->B0, waves 2,3 the 16 pieces of h2[col]->B1.
#pragma unroll
  for (int it = 0; it < 8; ++it) {
    int g = wave * 8 + it;  // 0..31
    int p = g & 15;
    uint4 v = *(const uint4*)((g < 16 ? hrow : hcol) + p * 8);
    *(uint4*)((g < 16 ? B0 : B1) + lane * STR + p * 8) = v;
  }

  // eattr A-frags in registers (K-step 8 of GEMM1)
  const int m = lane & 15, q = lane >> 4;
  bf16x8 ef[4];
#pragma unroll
  for (int mt = 0; mt < 4; ++mt) {
    union { u16 s[8]; uint4 u; bf16x8 v; } t;
    t.u = make_uint4(0u, 0u, 0u, 0u);
    if (q == 0) {
      float4 a = *(const float4*)(eattr + (size_t)(e0 + mt * 16 + m) * 4);
      t.s[0] = f2bf(a.x); t.s[1] = f2bf(a.y); t.s[2] = f2bf(a.z); t.s[3] = f2bf(a.w);
    }
    ef[mt] = t.v;
  }
  __syncthreads();

  const int aoff = m * STR + q * 8;
  f32x4 acc[4][2];

  zero_acc(acc);  // GEMM1: K=288: [B0 | B1 | eattr-regs]
  wgemm<9>(pW1, [&](int ks, int mt) -> bf16x8 {
    if (ks < 4) return ld8(B0 + aoff + mt * 16 * STR + ks * 32);
    if (ks < 8) return ld8(B1 + aoff + mt * 16 * STR + (ks - 4) * 32);
    return ef[mt];
  }, acc, lane, wave);
  epi_store<true>(B2, acc, b1, lane, wave);  // H -> B2 (nobody reads B2 yet)
  __syncthreads();

  zero_acc(acc);  // GEMM2: ea1 = W2 x H
  wgemm<4>(pW2, [&](int ks, int mt) -> bf16x8 {
    return ld8(B2 + aoff + mt * 16 * STR + ks * 32);
  }, acc, lane, wave);
  epi_store<false>(B1, acc, b2, lane, wave);  // ea1 -> B1 (B1's GEMM1 reads done)
  __syncthreads();
  flush_buf(B1, ea1, e0, tid);

  if (e0 < N_NODES) {  // h3 only ever gathered at indices < N
    zero_acc(acc);  // GEMM3: K=256: [B0 h2row | B1 ea1]
    wgemm<8>(pW3, [&](int ks, int mt) -> bf16x8 {
      if (ks < 4) return ld8(B0 + aoff + mt * 16 * STR + ks * 32);
      return ld8(B1 + aoff + mt * 16 * STR + (ks - 4) * 32);
    }, acc, lane, wave);
    epi_store<true>(B2, acc, b3, lane, wave);  // H' -> B2 (GEMM2 reads long done)
    __syncthreads();
    zero_acc(acc);  // GEMM4
    wgemm<4>(pW4, [&](int ks, int mt) -> bf16x8 {
      return ld8(B2 + aoff + mt * 16 * STR + ks * 32);
    }, acc, lane, wave);
    epi_store<false>(B0, acc, b4, lane, wave);  // h3 -> B0
    __syncthreads();
    flush_buf(B0, h3, e0, tid);
  }
}

// ---- gnn2 + fm1 + BN-stats ----
__global__ __launch_bounds__(256, 3) void k_gnn2(
    const int* __restrict__ eidx, const u16* __restrict__ h3, u16* ea1z,
    const u16* __restrict__ pW5, const u16* __restrict__ pW6, const u16* __restrict__ pW7,
    const float* __restrict__ b5, const float* __restrict__ b6, const float* __restrict__ b7,
    float* __restrict__ partials) {
  __shared__ __align__(16) u16 B0[64 * STR], B1[64 * STR], B2[64 * STR];
  const int tid = threadIdx.x, lane = tid & 63, wave = tid >> 6;
  const int e0 = blockIdx.x * 64;
  const int* rowI = eidx;
  const int* colI = eidx + N_EDGES;
  const int idr = rowI[e0 + lane], idc = colI[e0 + lane];
  const u16* hrow = h3 + (size_t)idr * HID;
  const u16* hcol = h3 + (size_t)idc * HID;

#pragma unroll
  for (int it = 0; it < 8; ++it) {
    int g = wave * 8 + it;  // 0..31
    int p = g & 15;
    uint4 v = *(const uint4*)((g < 16 ? hrow : hcol) + p * 8);
    *(uint4*)((g < 16 ? B0 : B1) + lane * STR + p * 8) = v;
  }
#pragma unroll
  for (int it = 0; it < 4; ++it) {  // stage own ea1 rows (coalesced)
    int cid = tid + it * 256, e = cid >> 4, p = cid & 15;
    uint4 v = *(const uint4*)(ea1z + (size_t)(e0 + e) * HID + p * 8);
    *(uint4*)(B2 + e * STR + p * 8) = v;
  }
  __syncthreads();

  const int m = lane & 15, q = lane >> 4;
  const int aoff = m * STR + q * 8;
  f32x4 acc[4][2];

  zero_acc(acc);  // GEMM1: K=384: [B0 | B1 | B2]
  wgemm<12>(pW5, [&](int ks, int mt) -> bf16x8 {
    if (ks < 4) return ld8(B0 + aoff + mt * 16 * STR + ks * 32);
    if (ks < 8) return ld8(B1 + aoff + mt * 16 * STR + (ks - 4) * 32);
    return ld8(B2 + aoff + mt * 16 * STR + (ks - 8) * 32);
  }, acc, lane, wave);
  __syncthreads();  // all waves done reading B0 before H overwrites it
  epi_store<true>(B0, acc, b5, lane, wave);
  __syncthreads();

  zero_acc(acc);  // GEMM2: ea2
  wgemm<4>(pW6, [&](int ks, int mt) -> bf16x8 {
    return ld8(B0 + aoff + mt * 16 * STR + ks * 32);
  }, acc, lane, wave);
  epi_store<false>(B1, acc, b6, lane, wave);
  __syncthreads();

  zero_acc(acc);  // GEMM3: z = fm1(ea2)
  wgemm<4>(pW7, [&](int ks, int mt) -> bf16x8 {
    return ld8(B1 + aoff + mt * 16 * STR + ks * 32);
  }, acc, lane, wave);

  // z epilogue + per-channel BN partial sums (this wave covers ch wave*32..+31)
  {
    const int c = lane & 15;
    const float bb0 = b7[wave * 32 + c], bb1 = b7[wave * 32 + 16 + c];
    float s0 = 0.f, q0 = 0.f, s1 = 0.f, q1 = 0.f;
#pragma unroll
    for (int mt = 0; mt < 4; ++mt)
#pragma unroll
      for (int r = 0; r < 4; ++r) {
        float v0 = acc[mt][0][r] + bb0;
        float v1 = acc[mt][1][r] + bb1;
        s0 += v0; q0 += v0 * v0;
        s1 += v1; q1 += v1 * v1;
        int row = mt * 16 + q * 4 + r;
        B2[row * STR + wave * 32 + c] = f2bf(v0);
        B2[row * STR + wave * 32 + 16 + c] = f2bf(v1);
      }
    s0 += __shfl_xor(s0, 16); s0 += __shfl_xor(s0, 32);
    q0 += __shfl_xor(q0, 16); q0 += __shfl_xor(q0, 32);
    s1 += __shfl_xor(s1, 16); s1 += __shfl_xor(s1, 32);
    q1 += __shfl_xor(q1, 16); q1 += __shfl_xor(q1, 32);
    if (lane < 16) {
      int base = blockIdx.x * 256;
      partials[base + wave * 32 + lane] = s0;
      partials[base + wave * 32 + 16 + lane] = s1;
      partials[base + 128 + wave * 32 + lane] = q0;
      partials[base + 128 + wave * 32 + 16 + lane] = q1;
    }
  }
  __syncthreads();
  flush_buf(B2, ea1z, e0, tid);  // z overwrites own ea1 rows (already consumed)
}

__global__ void k_reduce(const float* __restrict__ partials, float* __restrict__ bnacc) {
  int t = threadIdx.x;  // 256
  float s = 0.f;
  for (int b = blockIdx.x; b < NBLK; b += 64) s += partials[b * 256 + t];
  atomicAdd(&bnacc[t], s);
}

__global__ void k_bnfin(const float* __restrict__ bnacc, const float* __restrict__ bn_g,
                        const float* __restrict__ bn_b, float* __restrict__ ss) {
  int t = threadIdx.x;  // 128
  float inv = 1.0f / (float)N_EDGES;
  float mu = bnacc[t] * inv;
  float var = bnacc[128 + t] * inv - mu * mu;
  float sc = bn_g[t] * rsqrtf(var + 1e-5f);
  ss[t] = sc;
  ss[128 + t] = bn_b[t] - mu * sc;
}

// ---- head: one edge per thread, streaming, no cross-lane reductions ----
__global__ __launch_bounds__(256) void k_head(const u16* __restrict__ z,
                                              const float* __restrict__ ss,
                                              const float* __restrict__ w2,
                                              const float* __restrict__ b2,
                                              float* __restrict__ out) {
  __shared__ float sh_s[128], sh_h[128], sh_w0[128], sh_w1[128], sh_w2[128];
  const int tid = threadIdx.x;
  if (tid < 128) {
    sh_s[tid] = ss[tid];
    sh_h[tid] = ss[128 + tid];
    sh_w0[tid] = w2[tid];
    sh_w1[tid] = w2[128 + tid];
    sh_w2[tid] = w2[256 + tid];
  }
  __syncthreads();
  const int e = blockIdx.x * 256 + tid;
  if (e >= N_EDGES) return;
  float a0 = b2[0], a1 = b2[1], a2 = b2[2];
  const u16* zr = z + (size_t)e * HID;
#pragma unroll
  for (int p = 0; p < 16; ++p) {
    uint4 v = *(const uint4*)(zr + p * 8);
    unsigned wv[4] = {v.x, v.y, v.z, v.w};
#pragma unroll
    for (int k = 0; k < 4; ++k) {
      int ch = p * 8 + k * 2;
      float lo = bf2f(wv[k] & 0xffffu), hi = bf2f(wv[k] >> 16);
      float r0 = fmaxf(fmaf(lo, sh_s[ch], sh_h[ch]), 0.f);
      float r1 = fmaxf(fmaf(hi, sh_s[ch + 1], sh_h[ch + 1]), 0.f);
      a0 += r0 * sh_w0[ch] + r1 * sh_w0[ch + 1];
      a1 += r0 * sh_w1[ch] + r1 * sh_w1[ch + 1];
      a2 += r0 * sh_w2[ch] + r1 * sh_w2[ch + 1];
    }
  }
  out[e * 3 + 0] = a0;
  out[e * 3 + 1] = a1;
  out[e * 3 + 2] = a2;
}

extern "C" void kernel_launch(void* const* d_in, const int* in_sizes, int n_in,
                              void* d_out, int out_size, void* d_ws, size_t ws_size,
                              hipStream_t stream) {
  const float* x         = (const float*)d_in[0];
  const int* eidx        = (const int*)d_in[1];
  const float* eattr     = (const float*)d_in[2];
  const float* node_type = (const float*)d_in[4];
  const float* emb       = (const float*)d_in[5];
  const float* conv_w    = (const float*)d_in[6];
  const float* conv_b    = (const float*)d_in[7];
  const float* fuse_w    = (const float*)d_in[8];
  const float* fuse_b    = (const float*)d_in[9];
  const float* g1e_w1    = (const float*)d_in[10];
  const float* g1e_b1    = (const float*)d_in[11];
  const float* g1e_w2    = (const float*)d_in[12];
  const float* g1e_b2    = (const float*)d_in[13];
  const float* g1n_w1    = (const float*)d_in[14];
  const float* g1n_b1    = (const float*)d_in[15];
  const float* g1n_w2    = (const float*)d_in[16];
  const float* g1n_b2    = (const float*)d_in[17];
  const float* g2e_w1    = (const float*)d_in[18];
  const float* g2e_b1    = (const float*)d_in[19];
  const float* g2e_w2    = (const float*)d_in[20];
  const float* g2e_b2    = (const float*)d_in[21];
  // d_in[22..25] = g2n_* : dead code in the reference (output unused)
  const float* fm_w1     = (const float*)d_in[26];
  const float* fm_b1     = (const float*)d_in[27];
  const float* bn_g      = (const float*)d_in[28];
  const float* bn_b      = (const float*)d_in[29];
  const float* fm_w2     = (const float*)d_in[30];
  const float* fm_b2     = (const float*)d_in[31];
  float* out = (float*)d_out;

  char* ws = (char*)d_ws;
  size_t off = 0;
  auto take = [&](size_t bytes) {
    void* p = ws + off;
    off = (off + bytes + 255) & ~(size_t)255;
    return p;
  };
  u16* h2   = (u16*)take((size_t)N_NODES * HID * 2);
  u16* h3   = (u16*)take((size_t)20032 * HID * 2);  // only rows < N ever gathered
  u16* ea1z = (u16*)take((size_t)N_EDGES * HID * 2);
  float* Mt    = (float*)take(20 * 128 * 4);
  float* C0    = (float*)take(128 * 4);
  float* Wnt   = (float*)take(128 * 4);
  float* bnacc = (float*)take(256 * 4);
  float* bnss  = (float*)take(256 * 4);
  float* partials = (float*)take((size_t)NBLK * 256 * 4);
  u16* pW1 = (u16*)take(9 * 4096 * 2);
  u16* pW2 = (u16*)take(4 * 4096 * 2);
  u16* pW3 = (u16*)take(8 * 4096 * 2);
  u16* pW4 = (u16*)take(4 * 4096 * 2);
  u16* pW5 = (u16*)take(12 * 4096 * 2);
  u16* pW6 = (u16*)take(4 * 4096 * 2);
  u16* pW7 = (u16*)take(4 * 4096 * 2);

  hipMemsetAsync(bnacc, 0, 256 * 4, stream);
  k_fold<<<1, 128, 0, stream>>>(emb, conv_w, conv_b, fuse_w, fuse_b, Mt, C0, Wnt);

  PackArgs pa;
  const float* srcs[7] = {g1e_w1, g1e_w2, g1n_w1, g1n_w2, g2e_w1, g2e_w2, fm_w1};
  u16* dsts[7] = {pW1, pW2, pW3, pW4, pW5, pW6, pW7};
  int kins[7] = {260, 128, 256, 128, 384, 128, 128};
  int kst[7] = {9, 4, 8, 4, 12, 4, 4};
  int cum = 0;
  for (int i = 0; i < 7; ++i) {
    pa.src[i] = srcs[i]; pa.dst[i] = dsts[i]; pa.Kin[i] = kins[i];
    pa.ksCum[i] = cum; cum += kst[i];
  }
  pa.ksCum[7] = cum;  // 45
  k_pack<<<45, 256, 0, stream>>>(pa);

  k_encode<<<N_NODES / 2, 256, 0, stream>>>(x, node_type, Mt, C0, Wnt, h2);
  k_gnn1<<<NBLK, 256, 0, stream>>>(eidx, eattr, h2, pW1, pW2, pW3, pW4,
                                   g1e_b1, g1e_b2, g1n_b1, g1n_b2, ea1z, h3);
  k_gnn2<<<NBLK, 256, 0, stream>>>(eidx, h3, ea1z, pW5, pW6, pW7,
                                   g2e_b1, g2e_b2, fm_b1, partials);
  k_reduce<<<64, 256, 0, stream>>>(partials, bnacc);
  k_bnfin<<<1, 128, 0, stream>>>(bnacc, bn_g, bn_b, bnss);
  k_head<<<(N_EDGES + 255) / 256, 256, 0, stream>>>(ea1z, bnss, fm_w2, fm_b2, out);
}